// Round 3
// baseline (121.564 us; speedup 1.0000x reference)
//
#include <hip/hip_runtime.h>

typedef __attribute__((ext_vector_type(8))) short short8;
typedef __attribute__((ext_vector_type(4))) float f32x4;

#define LNP_YSTRIDE 1032   // 16 rows x (1024+8) bf16 (target path)
#define DYSTR 136          // drug-H path: 64 rows x (128+8) bf16

__device__ __forceinline__ unsigned short f2bf(float f) {
  union { float f; unsigned u; } v; v.f = f;
  unsigned r = v.u + 0x7FFFu + ((v.u >> 16) & 1u);  // RNE
  return (unsigned short)(r >> 16);
}
__device__ __forceinline__ unsigned pack2(float a, float b) {
  return (unsigned)f2bf(a) | ((unsigned)f2bf(b) << 16);
}
__device__ __forceinline__ short8 packW(float4 a, float4 b) {
  union { short8 s; unsigned u[4]; } r;
  r.u[0] = pack2(a.x, a.y); r.u[1] = pack2(a.z, a.w);
  r.u[2] = pack2(b.x, b.y); r.u[3] = pack2(b.z, b.w);
  return r.s;
}

// 4-row target LN + projection: 512 blocks (2/CU). Wave w LNs row w (one row,
// single load round-trip + one reduce chain before the barrier); MFMA K=1024
// split 4 ways (wave w: k-steps w*8..w*8+7), both h-tiles per wave.
// Yl rows 4..15 are uninitialized — D rows are independent; only rows 0..3 kept.
__device__ __forceinline__ void lnproj4_t(
    const float* __restrict__ X, const float* __restrict__ g, const float* __restrict__ bia,
    const float* __restrict__ W, const float* __restrict__ pb, const float* __restrict__ msk,
    unsigned short* __restrict__ outb, int row0, unsigned short* Yl, float* pd, int tid)
{
  const int w = tid >> 6, lid = tid & 63, l = tid & 15, q = (tid >> 4) & 3;
  const f32x4 zero = {0.f, 0.f, 0.f, 0.f};

  {
    const float* xr = X + (size_t)(row0 + w) * 1024;
    float4 v[4];
    float s = 0.f, s2 = 0.f;
    #pragma unroll
    for (int k = 0; k < 4; ++k) {
      v[k] = *(const float4*)(xr + 4 * lid + 256 * k);
      s  += (v[k].x + v[k].y) + (v[k].z + v[k].w);
      s2 += (v[k].x * v[k].x + v[k].y * v[k].y) + (v[k].z * v[k].z + v[k].w * v[k].w);
    }
    #pragma unroll
    for (int off = 32; off >= 1; off >>= 1) { s += __shfl_xor(s, off, 64); s2 += __shfl_xor(s2, off, 64); }
    const float mu = s * (1.f / 1024.f);
    const float rs = rsqrtf(s2 * (1.f / 1024.f) - mu * mu + 1e-5f);
    #pragma unroll
    for (int k = 0; k < 4; ++k) {
      float4 gg = *(const float4*)(g + 4 * lid + 256 * k);
      float4 bb = *(const float4*)(bia + 4 * lid + 256 * k);
      unsigned* yd = (unsigned*)(Yl + w * LNP_YSTRIDE + 4 * lid + 256 * k);
      yd[0] = pack2((v[k].x - mu) * rs * gg.x + bb.x, (v[k].y - mu) * rs * gg.y + bb.y);
      yd[1] = pack2((v[k].z - mu) * rs * gg.z + bb.z, (v[k].w - mu) * rs * gg.w + bb.w);
    }
  }
  __syncthreads();

  f32x4 acc0 = zero, acc1 = zero;
  #pragma unroll
  for (int ss = 0; ss < 8; ++ss) {
    const int s = w * 8 + ss;
    short8 af = *(const short8*)(Yl + l * LNP_YSTRIDE + s * 32 + q * 8);   // A[m][k]
    const float* wp0 = W + (size_t)l * 1024 + s * 32 + q * 8;              // h = l
    const float* wp1 = W + (size_t)(16 + l) * 1024 + s * 32 + q * 8;       // h = 16+l
    acc0 = __builtin_amdgcn_mfma_f32_16x16x32_bf16(af, packW(*(const float4*)wp0, *(const float4*)(wp0 + 4)), acc0, 0, 0, 0);
    acc1 = __builtin_amdgcn_mfma_f32_16x16x32_bf16(af, packW(*(const float4*)wp1, *(const float4*)(wp1 + 4)), acc1, 0, 0, 0);
  }
  if (w > 0 && q == 0) {
    #pragma unroll
    for (int r = 0; r < 4; ++r) {                     // D rows 0..3 only
      pd[(w - 1) * 128 + r * 16 + l]      = acc0[r];
      pd[(w - 1) * 128 + 64 + r * 16 + l] = acc1[r];
    }
  }
  __syncthreads();
  if (w == 0 && q == 0) {
    #pragma unroll
    for (int ht = 0; ht < 2; ++ht) {
      const int h = ht * 16 + l;
      const float pbv = pb[h];
      #pragma unroll
      for (int r = 0; r < 4; ++r) {
        const int rg = row0 + r;
        float val = (ht ? acc1[r] : acc0[r]) + pbv;
        #pragma unroll
        for (int k = 0; k < 3; ++k) val += pd[k * 128 + ht * 64 + r * 16 + l];
        outb[(size_t)rg * 32 + h] = f2bf(val * msk[rg]);
      }
    }
  }
}

// H-block: recompute drug LN+proj for batch b (waves independent, NO barriers),
// then H[b][m][ic] = sum_e W_out[ic*32+e] * df[b][m][e] for this block's 64 ic.
__device__ __forceinline__ void drug_h(
    const float* __restrict__ drg, const float* __restrict__ g, const float* __restrict__ bia,
    const float* __restrict__ W_d, const float* __restrict__ b_d, const float* __restrict__ dmask,
    const float* __restrict__ W_out, unsigned short* __restrict__ Hb,
    int b, int icg, unsigned short* Yl, int tid)
{
  const int w = tid >> 6, lid = tid & 63, l = tid & 15, q = (tid >> 4) & 3;
  const f32x4 zero = {0.f, 0.f, 0.f, 0.f};

  // Step A: LN rows w*16 .. w*16+15 of drg[b] -> Yl (bf16, stride DYSTR)
  #pragma unroll
  for (int rr = 0; rr < 16; ++rr) {
    const int row = w * 16 + rr;
    const float* xr = drg + (size_t)(b * 64 + row) * 128;
    float2 v = *(const float2*)(xr + 2 * lid);
    float s = v.x + v.y, s2 = v.x * v.x + v.y * v.y;
    #pragma unroll
    for (int off = 32; off >= 1; off >>= 1) { s += __shfl_xor(s, off, 64); s2 += __shfl_xor(s2, off, 64); }
    const float mu = s * (1.f / 128.f);
    const float rs = rsqrtf(s2 * (1.f / 128.f) - mu * mu + 1e-5f);
    float2 gg = *(const float2*)(g + 2 * lid);
    float2 bb = *(const float2*)(bia + 2 * lid);
    *(unsigned*)(Yl + row * DYSTR + 2 * lid) =
        pack2((v.x - mu) * rs * gg.x + bb.x, (v.y - mu) * rs * gg.y + bb.y);
  }

  // Step B: df = Y @ W_d^T + b_d, masked.  A = W_d rows (h), B = Y rows (m=w*16+l).
  f32x4 acc0 = zero, acc1 = zero;
  #pragma unroll
  for (int s = 0; s < 4; ++s) {
    short8 bf = *(const short8*)(Yl + (w * 16 + l) * DYSTR + s * 32 + q * 8);
    const float* wp0 = W_d + (size_t)l * 128 + s * 32 + q * 8;
    const float* wp1 = W_d + (size_t)(16 + l) * 128 + s * 32 + q * 8;
    acc0 = __builtin_amdgcn_mfma_f32_16x16x32_bf16(packW(*(const float4*)wp0, *(const float4*)(wp0 + 4)), bf, acc0, 0, 0, 0);
    acc1 = __builtin_amdgcn_mfma_f32_16x16x32_bf16(packW(*(const float4*)wp1, *(const float4*)(wp1 + 4)), bf, acc1, 0, 0, 0);
  }
  const float dmv = dmask[b * 64 + w * 16 + l];     // col m = l
  const float4 bd0 = *(const float4*)(b_d + q * 4);
  const float4 bd1 = *(const float4*)(b_d + 16 + q * 4);
  unsigned u0a = pack2((acc0[0] + bd0.x) * dmv, (acc0[1] + bd0.y) * dmv);
  unsigned u0b = pack2((acc0[2] + bd0.z) * dmv, (acc0[3] + bd0.w) * dmv);
  unsigned u1a = pack2((acc1[0] + bd1.x) * dmv, (acc1[1] + bd1.y) * dmv);
  unsigned u1b = pack2((acc1[2] + bd1.z) * dmv, (acc1[3] + bd1.w) * dmv);

  // In-wave transpose: thread (q,l) needs df[m=w*16+l][e = q*8 .. q*8+7].
  const int srcA = ((q & 1) << 5) + l;
  const int srcB = srcA + 16;
  unsigned a0 = __shfl((int)u0a, srcA, 64), a1 = __shfl((int)u1a, srcA, 64);
  unsigned b0 = __shfl((int)u0b, srcA, 64), b1 = __shfl((int)u1b, srcA, 64);
  unsigned c0 = __shfl((int)u0a, srcB, 64), c1 = __shfl((int)u1a, srcB, 64);
  unsigned d0 = __shfl((int)u0b, srcB, 64), d1 = __shfl((int)u1b, srcB, 64);
  const bool hi = (q >= 2);
  union { short8 s; unsigned u[4]; } bfrag;
  bfrag.u[0] = hi ? a1 : a0;
  bfrag.u[1] = hi ? b1 : b0;
  bfrag.u[2] = hi ? c1 : c0;
  bfrag.u[3] = hi ? d1 : d0;

  // Step C: H slice. A = W_out rows (ic, CONTIGUOUS), B = df frag.
  const int m = w * 16 + l;
  #pragma unroll
  for (int u = 0; u < 4; ++u) {
    const int ic0 = icg * 64 + u * 16;
    const float* ap = W_out + (size_t)(ic0 + l) * 32 + q * 8;
    short8 af = packW(*(const float4*)ap, *(const float4*)(ap + 4));
    f32x4 d = __builtin_amdgcn_mfma_f32_16x16x32_bf16(af, bfrag.s, zero, 0, 0, 0);
    uint2 hv; hv.x = pack2(d[0], d[1]); hv.y = pack2(d[2], d[3]);
    *(uint2*)(Hb + (size_t)(b * 64 + m) * 4096 + ic0 + q * 4) = hv;
  }
}

// k_pre grid (896 blocks): [0,512) target LN+proj (4 rows each);
// [512,768) drug LN+proj+H; [768,896) mask out.
__global__ __launch_bounds__(256) void k_pre(
    const float* __restrict__ tgt, const float* __restrict__ drg,
    const float* __restrict__ tmask, const float* __restrict__ dmask,
    const float* __restrict__ ln_t_g, const float* __restrict__ ln_t_b,
    const float* __restrict__ ln_d_g, const float* __restrict__ ln_d_b,
    const float* __restrict__ W_t, const float* __restrict__ b_t,
    const float* __restrict__ W_d, const float* __restrict__ b_d,
    const float* __restrict__ W_out,
    unsigned short* __restrict__ tfb, unsigned short* __restrict__ Hb,
    float* __restrict__ mask_out)
{
  __shared__ unsigned short Yl[16 * LNP_YSTRIDE];
  __shared__ float pd[3 * 128];
  const int blk = blockIdx.x, tid = threadIdx.x;
  if (blk < 512) {
    lnproj4_t(tgt, ln_t_g, ln_t_b, W_t, b_t, tmask, tfb, blk * 4, Yl, pd, tid);
  } else if (blk < 768) {
    drug_h(drg, ln_d_g, ln_d_b, W_d, b_d, dmask, W_out, Hb,
           (blk - 512) >> 6, (blk - 512) & 63, Yl, tid);
  } else {
    const int base = ((blk - 768) * 256 + tid) * 4;   // flat index into [4,512,64]
    const int b = base >> 15;
    const float tm = tmask[base >> 6];
    float4 d = *(const float4*)(dmask + b * 64 + (base & 63));
    float4 o; o.x = tm * d.x; o.y = tm * d.y; o.z = tm * d.z; o.w = tm * d.w;
    *(float4*)(mask_out + base) = o;
  }
}

// k_main: out[b,n,m,i] = (sum_c H[b,m,i*32+c] * tf[b,n,c] + b_out[i]) * tm[n]*dm[m]
// Pure streaming GEMM, K=32, no LDS, no barriers. 2048 blocks.
// XCD-friendly decode: m in the low 3+ bits so the 8 ng-blocks sharing one
// (b,m) H-row (ids differing by 64 == 0 mod 8) land on the SAME XCD's L2.
__global__ __launch_bounds__(256) void k_main(
    const unsigned short* __restrict__ Hb, const unsigned short* __restrict__ tfb,
    const float* __restrict__ b_out, const float* __restrict__ tmask,
    const float* __restrict__ dmask, float* __restrict__ out)
{
  const int id = blockIdx.x;
  const int b = id >> 9, ng = (id >> 6) & 7, m = id & 63;
  const int tid = threadIdx.x, w = tid >> 6, l = tid & 15, q = (tid >> 4) & 3;
  const int n0 = ng * 64;
  const f32x4 zero = {0.f, 0.f, 0.f, 0.f};

  const unsigned short* hrow = Hb + (size_t)(b * 64 + m) * 4096;
  short8 a0 = *(const short8*)(hrow + (w * 32 + l) * 32 + q * 8);
  short8 a1 = *(const short8*)(hrow + (w * 32 + 16 + l) * 32 + q * 8);

  short8 bfr[4];
  #pragma unroll
  for (int t2 = 0; t2 < 4; ++t2)
    bfr[t2] = *(const short8*)(tfb + (size_t)(b * 512 + n0 + t2 * 16 + l) * 32 + q * 8);

  const float4 bo0 = *(const float4*)(b_out + w * 32 + q * 4);
  const float4 bo1 = *(const float4*)(b_out + w * 32 + 16 + q * 4);
  const float dmv = dmask[b * 64 + m];
  float tmv[4];
  #pragma unroll
  for (int t2 = 0; t2 < 4; ++t2)
    tmv[t2] = tmask[b * 512 + n0 + t2 * 16 + l] * dmv;

  #pragma unroll
  for (int t2 = 0; t2 < 4; ++t2) {
    const size_t rbase = ((size_t)(b * 512 + n0 + t2 * 16 + l) * 64 + m) * 128;
    const float s = tmv[t2];
    f32x4 d0 = __builtin_amdgcn_mfma_f32_16x16x32_bf16(a0, bfr[t2], zero, 0, 0, 0);
    f32x4 d1 = __builtin_amdgcn_mfma_f32_16x16x32_bf16(a1, bfr[t2], zero, 0, 0, 0);
    f32x4 o0, o1;
    o0[0] = (d0[0] + bo0.x) * s; o0[1] = (d0[1] + bo0.y) * s;
    o0[2] = (d0[2] + bo0.z) * s; o0[3] = (d0[3] + bo0.w) * s;
    o1[0] = (d1[0] + bo1.x) * s; o1[1] = (d1[1] + bo1.y) * s;
    o1[2] = (d1[2] + bo1.z) * s; o1[3] = (d1[3] + bo1.w) * s;
    *(f32x4*)(out + rbase + w * 32 + q * 4) = o0;
    *(f32x4*)(out + rbase + w * 32 + 16 + q * 4) = o1;
  }
}

extern "C" void kernel_launch(void* const* d_in, const int* in_sizes, int n_in,
                              void* d_out, int out_size, void* d_ws, size_t ws_size,
                              hipStream_t stream)
{
  const float* tgt    = (const float*)d_in[0];
  const float* drg    = (const float*)d_in[1];
  const float* tmask  = (const float*)d_in[2];
  const float* dmask  = (const float*)d_in[3];
  const float* ln_t_g = (const float*)d_in[4];
  const float* ln_t_b = (const float*)d_in[5];
  const float* ln_d_g = (const float*)d_in[6];
  const float* ln_d_b = (const float*)d_in[7];
  const float* W_t    = (const float*)d_in[8];
  const float* b_t    = (const float*)d_in[9];
  const float* W_d    = (const float*)d_in[10];
  const float* b_d    = (const float*)d_in[11];
  const float* W_out  = (const float*)d_in[12];
  const float* b_out  = (const float*)d_in[13];

  float* out = (float*)d_out;
  float* mask_out = out + (size_t)4 * 512 * 64 * 128;   // second output

  char* ws = (char*)d_ws;
  unsigned short* Hb  = (unsigned short*)(ws);            // 4*64*4096 bf16 = 2 MB
  unsigned short* tfb = (unsigned short*)(ws + 2097152);  // 2048*32 bf16 = 128 KB

  k_pre<<<dim3(896), dim3(256), 0, stream>>>(
      tgt, drg, tmask, dmask, ln_t_g, ln_t_b, ln_d_g, ln_d_b,
      W_t, b_t, W_d, b_d, W_out, tfb, Hb, mask_out);
  k_main<<<dim3(2048), dim3(256), 0, stream>>>(Hb, tfb, b_out, tmask, dmask, out);
}

// Round 4
// 116.238 us; speedup vs baseline: 1.0458x; 1.0458x over previous
//
#include <hip/hip_runtime.h>

typedef __attribute__((ext_vector_type(8))) short short8;
typedef __attribute__((ext_vector_type(4))) float f32x4;

#define LNP_YSTRIDE 1032   // 16 rows x (1024+8) bf16
#define GSTR 1048          // G tile row stride (bf16 elems)

__device__ __forceinline__ unsigned short f2bf(float f) {
  union { float f; unsigned u; } v; v.f = f;
  unsigned r = v.u + 0x7FFFu + ((v.u >> 16) & 1u);  // RNE
  return (unsigned short)(r >> 16);
}
__device__ __forceinline__ unsigned pack2(float a, float b) {
  return (unsigned)f2bf(a) | ((unsigned)f2bf(b) << 16);
}
__device__ __forceinline__ short8 packW(float4 a, float4 b) {
  union { short8 s; unsigned u[4]; } r;
  r.u[0] = pack2(a.x, a.y); r.u[1] = pack2(a.z, a.w);
  r.u[2] = pack2(b.x, b.y); r.u[3] = pack2(b.z, b.w);
  return r.s;
}

// 8-row target LN + projection: 256 blocks. Wave w LNs rows w*2..w*2+1;
// MFMA K=1024 split 4 ways (wave w: k-steps w*8..w*8+7), both h-tiles per wave.
// A rows 8..15 are uninitialized LDS — D rows are independent; only rows 0..7 stored.
__device__ __forceinline__ void lnproj8_t(
    const float* __restrict__ X, const float* __restrict__ g, const float* __restrict__ bia,
    const float* __restrict__ W, const float* __restrict__ pb, const float* __restrict__ msk,
    unsigned short* __restrict__ outb, int row0, unsigned short* Yl, float* pd, int tid)
{
  const int w = tid >> 6, lid = tid & 63, l = tid & 15, q = (tid >> 4) & 3;
  const f32x4 zero = {0.f, 0.f, 0.f, 0.f};

  #pragma unroll
  for (int rr = 0; rr < 2; ++rr) {
    const int row = w * 2 + rr;
    const float* xr = X + (size_t)(row0 + row) * 1024;
    float4 v[4];
    float s = 0.f, s2 = 0.f;
    #pragma unroll
    for (int k = 0; k < 4; ++k) {
      v[k] = *(const float4*)(xr + 4 * lid + 256 * k);
      s  += (v[k].x + v[k].y) + (v[k].z + v[k].w);
      s2 += (v[k].x * v[k].x + v[k].y * v[k].y) + (v[k].z * v[k].z + v[k].w * v[k].w);
    }
    #pragma unroll
    for (int off = 32; off >= 1; off >>= 1) { s += __shfl_xor(s, off, 64); s2 += __shfl_xor(s2, off, 64); }
    const float mu = s * (1.f / 1024.f);
    const float rs = rsqrtf(s2 * (1.f / 1024.f) - mu * mu + 1e-5f);
    #pragma unroll
    for (int k = 0; k < 4; ++k) {
      float4 gg = *(const float4*)(g + 4 * lid + 256 * k);
      float4 bb = *(const float4*)(bia + 4 * lid + 256 * k);
      unsigned* yd = (unsigned*)(Yl + row * LNP_YSTRIDE + 4 * lid + 256 * k);
      yd[0] = pack2((v[k].x - mu) * rs * gg.x + bb.x, (v[k].y - mu) * rs * gg.y + bb.y);
      yd[1] = pack2((v[k].z - mu) * rs * gg.z + bb.z, (v[k].w - mu) * rs * gg.w + bb.w);
    }
  }
  __syncthreads();

  // MFMA: wave w takes k-steps w*8..w*8+7 for BOTH h-tiles (h=l and h=16+l)
  f32x4 acc0 = zero, acc1 = zero;
  #pragma unroll
  for (int ss = 0; ss < 8; ++ss) {
    const int s = w * 8 + ss;
    short8 af = *(const short8*)(Yl + l * LNP_YSTRIDE + s * 32 + q * 8);   // A[m][k]
    const float* wp0 = W + (size_t)l * 1024 + s * 32 + q * 8;              // h = l
    const float* wp1 = W + (size_t)(16 + l) * 1024 + s * 32 + q * 8;       // h = 16+l
    acc0 = __builtin_amdgcn_mfma_f32_16x16x32_bf16(af, packW(*(const float4*)wp0, *(const float4*)(wp0 + 4)), acc0, 0, 0, 0);
    acc1 = __builtin_amdgcn_mfma_f32_16x16x32_bf16(af, packW(*(const float4*)wp1, *(const float4*)(wp1 + 4)), acc1, 0, 0, 0);
  }
  if (w > 0 && q < 2) {
    #pragma unroll
    for (int r = 0; r < 4; ++r) {
      const int rl = q * 4 + r;                        // D row 0..7
      pd[(w - 1) * 256 + rl * 16 + l]       = acc0[r];
      pd[(w - 1) * 256 + 128 + rl * 16 + l] = acc1[r];
    }
  }
  __syncthreads();
  if (w == 0 && q < 2) {
    #pragma unroll
    for (int ht = 0; ht < 2; ++ht) {
      const int h = ht * 16 + l;
      const float pbv = pb[h];
      #pragma unroll
      for (int r = 0; r < 4; ++r) {
        const int rl = q * 4 + r, rg = row0 + rl;
        float val = (ht ? acc1[r] : acc0[r]) + pbv;
        #pragma unroll
        for (int k = 0; k < 3; ++k) val += pd[k * 256 + ht * 128 + rl * 16 + l];
        outb[(size_t)rg * 32 + h] = f2bf(val * msk[rg]);
      }
    }
  }
}

// 16-row LN+proj — drug side (ROWLEN=128).
template<int ROWLEN>
__device__ __forceinline__ void lnproj(
    const float* __restrict__ X, const float* __restrict__ g, const float* __restrict__ bia,
    const float* __restrict__ W, const float* __restrict__ pb, const float* __restrict__ msk,
    unsigned short* __restrict__ outb, int row0, unsigned short* Yl, float* pd, int tid)
{
  const int w = tid >> 6, lid = tid & 63, l = tid & 15, q = (tid >> 4) & 3;

  #pragma unroll
  for (int rr = 0; rr < 4; ++rr) {
    const int row = w * 4 + rr;
    const float* xr = X + (size_t)(row0 + row) * ROWLEN;
    float2 v = *(const float2*)(xr + 2 * lid);
    float s = v.x + v.y, s2 = v.x * v.x + v.y * v.y;
    #pragma unroll
    for (int off = 32; off >= 1; off >>= 1) { s += __shfl_xor(s, off, 64); s2 += __shfl_xor(s2, off, 64); }
    const float mu = s * (1.f / ROWLEN);
    const float rs = rsqrtf(s2 * (1.f / ROWLEN) - mu * mu + 1e-5f);
    float2 gg = *(const float2*)(g + 2 * lid);
    float2 bb = *(const float2*)(bia + 2 * lid);
    *(unsigned*)(Yl + row * LNP_YSTRIDE + 2 * lid) =
        pack2((v.x - mu) * rs * gg.x + bb.x, (v.y - mu) * rs * gg.y + bb.y);
  }
  __syncthreads();

  const int KST = ROWLEN / 32;
  const int ht = w & 1, kh = w >> 1;
  const int h = ht * 16 + l;
  f32x4 acc = {0.f, 0.f, 0.f, 0.f};
  #pragma unroll
  for (int s = kh * (KST / 2); s < kh * (KST / 2) + KST / 2; ++s) {
    short8 af = *(const short8*)(Yl + l * LNP_YSTRIDE + s * 32 + q * 8);
    const float* wp = W + (size_t)h * ROWLEN + s * 32 + q * 8;
    short8 bf = packW(*(const float4*)wp, *(const float4*)(wp + 4));
    acc = __builtin_amdgcn_mfma_f32_16x16x32_bf16(af, bf, acc, 0, 0, 0);
  }
  if (w >= 2) {
    #pragma unroll
    for (int r = 0; r < 4; ++r) pd[ht * 256 + (q * 4 + r) * 16 + l] = acc[r];
  }
  __syncthreads();
  if (w < 2) {
    const float pbv = pb[h];
    #pragma unroll
    for (int r = 0; r < 4; ++r) {
      const int rg = row0 + q * 4 + r;
      float val = acc[r] + pd[ht * 256 + (q * 4 + r) * 16 + l] + pbv;
      val *= msk[rg];
      outb[(size_t)rg * 32 + h] = f2bf(val);
    }
  }
}

// k_pre grid (280 blocks): [0,256) target LN+proj (8 rows);
// [256,272) drug LN+proj (16 rows); [272,280) W_out transpose.
// (mask-out branch moved into k_main — removes a dispatch-round tail here.)
__global__ __launch_bounds__(256) void k_pre(
    const float* __restrict__ tgt, const float* __restrict__ drg,
    const float* __restrict__ tmask, const float* __restrict__ dmask,
    const float* __restrict__ ln_t_g, const float* __restrict__ ln_t_b,
    const float* __restrict__ ln_d_g, const float* __restrict__ ln_d_b,
    const float* __restrict__ W_t, const float* __restrict__ b_t,
    const float* __restrict__ W_d, const float* __restrict__ b_d,
    const float* __restrict__ W_out,
    unsigned short* __restrict__ w3pp, unsigned short* __restrict__ tfb,
    unsigned short* __restrict__ dfb)
{
  __shared__ unsigned short Yl[16 * LNP_YSTRIDE];
  __shared__ float pd[3 * 256];
  const int blk = blockIdx.x, tid = threadIdx.x;
  if (blk < 256) {
    lnproj8_t(tgt, ln_t_g, ln_t_b, W_t, b_t, tmask, tfb, blk * 8, Yl, pd, tid);
  } else if (blk < 272) {
    lnproj<128>(drg, ln_d_g, ln_d_b, W_d, b_d, dmask, dfb, (blk - 256) * 16, Yl, pd, tid);
  } else {
    const int tg = (blk - 272) * 256 + tid;
    #pragma unroll
    for (int rep = 0; rep < 2; ++rep) {
      const int f = tg + rep * 2048;
      const int i = f >> 5, e = f & 31;
      unsigned short us[32];
      #pragma unroll
      for (int c = 0; c < 32; ++c) us[c] = f2bf(W_out[i * 1024 + c * 32 + e]);
      unsigned* dst = (unsigned*)(w3pp + (size_t)f * 32);
      #pragma unroll
      for (int j = 0; j < 16; ++j) dst[j] = (unsigned)us[2 * j] | ((unsigned)us[2 * j + 1] << 16);
    }
  }
}

// k_main (R0 structure — best measured): 512 blocks = b(4) x n-tile16(32) x i-quarter(4).
// iq==0 blocks additionally write the mask output for their 16 n-rows (overlaps phase 1).
__global__ __launch_bounds__(256) void k_main(
    const unsigned short* __restrict__ w3pp, const unsigned short* __restrict__ tfb,
    const unsigned short* __restrict__ dfb, const float* __restrict__ b_out,
    const float* __restrict__ tmask, const float* __restrict__ dmask,
    float* __restrict__ out, float* __restrict__ mask_out)
{
  __shared__ unsigned short Gl[16 * GSTR];   // 33.5 KB
  const int id = blockIdx.x;
  const int b = id >> 7, n16 = (id >> 2) & 31, iq = id & 3;
  const int n0 = n16 * 16, i0 = iq * 32;
  const int tid = threadIdx.x, w = tid >> 6, l = tid & 15, q = (tid >> 4) & 3;

  if (iq == 0) {
    // mask_out[b, n0+nl, m] = tmask[b,n]*dmask[b,m]; 16 rows x 64 m = 256 thr x 4
    const int nl = tid >> 4, m4 = (tid & 15) * 4;
    const float tm = tmask[b * 512 + n0 + nl];
    float4 dv = *(const float4*)(dmask + b * 64 + m4);
    float4 o; o.x = tm * dv.x; o.y = tm * dv.y; o.z = tm * dv.z; o.w = tm * dv.w;
    *(float4*)(mask_out + ((size_t)(b * 512 + n0 + nl)) * 64 + m4) = o;
  }

  short8 atf = *(const short8*)(tfb + (size_t)(b * 512 + n0 + l) * 32 + q * 8);
  short8 bdf[4];
  #pragma unroll
  for (int mt = 0; mt < 4; ++mt)
    bdf[mt] = *(const short8*)(dfb + (size_t)(b * 64 + mt * 16 + l) * 32 + q * 8);

  const f32x4 zero = {0.f, 0.f, 0.f, 0.f};

  // Phase 1: G[n,i,e] = tf @ W3 for this i-quarter (16 frag-cols per wave)
  for (int t = w * 16; t < w * 16 + 16; ++t) {
    const int f = i0 * 32 + t * 16 + l;
    short8 bw = *(const short8*)(w3pp + (size_t)f * 32 + q * 8);   // B[c][f]
    f32x4 d = __builtin_amdgcn_mfma_f32_16x16x32_bf16(atf, bw, zero, 0, 0, 0);
    const int floc = t * 16 + l, ip = floc >> 5, e = floc & 31;
    #pragma unroll
    for (int r = 0; r < 4; ++r)
      Gl[(q * 4 + r) * GSTR + ip * 32 + e] = f2bf(d[r]);   // row n = q*4+r
  }
  __syncthreads();

  const float4 bo0 = *(const float4*)(b_out + i0 + q * 4);
  const float4 bo1 = *(const float4*)(b_out + i0 + 16 + q * 4);
  float dm[4];
  #pragma unroll
  for (int mt = 0; mt < 4; ++mt) dm[mt] = dmask[b * 64 + mt * 16 + l];

  // Phase 2: A=G (M=i), B=df (N=m) -> D rows consecutive i -> float4 stores
  for (int j = 0; j < 8; ++j) {
    const int p = w * 8 + j, n = p >> 1, it = p & 1;
    short8 ag = *(const short8*)(Gl + n * GSTR + (it * 16 + l) * 32 + q * 8);
    const float tmv = tmask[b * 512 + n0 + n];
    const float4 bo = it ? bo1 : bo0;
    const size_t obase = ((size_t)(b * 512 + n0 + n) * 64) * 128 + (size_t)(i0 + it * 16 + q * 4);
    #pragma unroll
    for (int mt = 0; mt < 4; ++mt) {
      f32x4 d = __builtin_amdgcn_mfma_f32_16x16x32_bf16(ag, bdf[mt], zero, 0, 0, 0);
      const float s = tmv * dm[mt];
      float4 o;
      o.x = (d[0] + bo.x) * s; o.y = (d[1] + bo.y) * s;
      o.z = (d[2] + bo.z) * s; o.w = (d[3] + bo.w) * s;
      *(float4*)(out + obase + (size_t)(mt * 16 + l) * 128) = o;
    }
  }
}

extern "C" void kernel_launch(void* const* d_in, const int* in_sizes, int n_in,
                              void* d_out, int out_size, void* d_ws, size_t ws_size,
                              hipStream_t stream)
{
  const float* tgt    = (const float*)d_in[0];
  const float* drg    = (const float*)d_in[1];
  const float* tmask  = (const float*)d_in[2];
  const float* dmask  = (const float*)d_in[3];
  const float* ln_t_g = (const float*)d_in[4];
  const float* ln_t_b = (const float*)d_in[5];
  const float* ln_d_g = (const float*)d_in[6];
  const float* ln_d_b = (const float*)d_in[7];
  const float* W_t    = (const float*)d_in[8];
  const float* b_t    = (const float*)d_in[9];
  const float* W_d    = (const float*)d_in[10];
  const float* b_d    = (const float*)d_in[11];
  const float* W_out  = (const float*)d_in[12];
  const float* b_out  = (const float*)d_in[13];

  float* out = (float*)d_out;
  float* mask_out = out + (size_t)4 * 512 * 64 * 128;   // second output

  char* ws = (char*)d_ws;
  unsigned short* w3pp = (unsigned short*)(ws);                    // 4096*32 bf16 = 256 KB
  unsigned short* tfb  = (unsigned short*)(ws + 262144);           // 2048*32 bf16 = 128 KB
  unsigned short* dfb  = (unsigned short*)(ws + 262144 + 131072);  // 256*32 bf16 = 16 KB

  k_pre<<<dim3(280), dim3(256), 0, stream>>>(
      tgt, drg, tmask, dmask, ln_t_g, ln_t_b, ln_d_g, ln_d_b,
      W_t, b_t, W_d, b_d, W_out, w3pp, tfb, dfb);
  k_main<<<dim3(512), dim3(256), 0, stream>>>(
      w3pp, tfb, dfb, b_out, tmask, dmask, out, mask_out);
}